// Round 19
// baseline (443.577 us; speedup 1.0000x reference)
//
#include <hip/hip_runtime.h>
#include <hip/hip_bf16.h>

using bf16 = __hip_bfloat16;
typedef __bf16 bf16x8 __attribute__((ext_vector_type(8)));
typedef float f32x4 __attribute__((ext_vector_type(4)));

#define DEV __device__ __forceinline__

// async global->LDS, 16B per lane. LDS dest = wave-uniform base + lane*16.
DEV void gload16(const void* g, void* l) {
  __builtin_amdgcn_global_load_lds((__attribute__((address_space(1))) void*)(g),
                                   (__attribute__((address_space(3))) void*)(l), 16, 0, 0);
}

DEV void mfma16(int4 a, int4 b, f32x4& c) {
  c = __builtin_amdgcn_mfma_f32_16x16x32_bf16(
      __builtin_bit_cast(bf16x8, a), __builtin_bit_cast(bf16x8, b), c, 0, 0, 0);
}

DEV unsigned short bfb(float x) { return __builtin_bit_cast(unsigned short, __float2bfloat16(x)); }

DEV int cvtpk(float lo, float hi) {
  int r;
  asm("v_cvt_pk_bf16_f32 %0, %1, %2" : "=v"(r) : "v"(lo), "v"(hi));
  return r;
}

DEV float b2f(unsigned short u) {
  unsigned int v = (unsigned int)u << 16;
  return __builtin_bit_cast(float, v);
}

// fast exact-erf GELU (A&S 7.1.26, |err|<=2e-7 — far below bf16 rounding)
DEV float gelu_f(float h) {
  float xr = h * 0.70710678118f;
  float ax = fabsf(xr);
  float t = __builtin_amdgcn_rcpf(fmaf(0.3275911f, ax, 1.f));
  float poly = fmaf(fmaf(fmaf(fmaf(1.061405429f, t, -1.453152027f), t, 1.421413741f),
                         t, -0.284496736f), t, 0.254829592f) * t;
  float e = __expf(-xr * xr);
  float erfv = copysignf(1.f - poly * e, xr);
  return 0.5f * h * (1.f + erfv);
}

// ---------------- weight convert: fp32 [K][N] -> bf16 W^T [N][K] (optionally QKV-permuted rows)
template<bool PERM>
__global__ __launch_bounds__(256) void wconv(const float* __restrict__ s0, const float* __restrict__ s1,
                                             const float* __restrict__ s2, const float* __restrict__ s3,
                                             bf16* d0, bf16* d1, bf16* d2, bf16* d3, int K, int N) {
  const float* S[4] = {s0, s1, s2, s3};
  bf16* Dd[4] = {d0, d1, d2, d3};
  const float* __restrict__ src = S[blockIdx.z];
  bf16* __restrict__ dst = Dd[blockIdx.z];
  __shared__ float tile[32][33];
  int tx = threadIdx.x, ty = threadIdx.y;
  int n0 = blockIdx.x * 32, k0 = blockIdx.y * 32;
#pragma unroll
  for (int i = 0; i < 4; i++) tile[ty + 8 * i][tx] = src[(size_t)(k0 + ty + 8 * i) * N + n0 + tx];
  __syncthreads();
#pragma unroll
  for (int i = 0; i < 4; i++) {
    int n = n0 + ty + 8 * i;
    int np;
    if (PERM) { // orig col n = dd*36 + kk*12 + h  ->  np = kk*768 + h*64 + dd
      int dd = n / 36; int r = n - dd * 36; int kk = r / 12; int h = r - kk * 12;
      np = kk * 768 + h * 64 + dd;
    } else np = n;
    dst[(size_t)np * K + k0 + tx] = __float2bfloat16(tile[tx][ty + 8 * i]);
  }
}

// ---------------- LayerNorm (fp32 in) -> bf16 out, both streams in one launch
__global__ __launch_bounds__(192) void ln2(const float* __restrict__ xa, const float* __restrict__ xb,
                                           const float* __restrict__ ga, const float* __restrict__ ba,
                                           const float* __restrict__ gb, const float* __restrict__ bb,
                                           bf16* __restrict__ out) {
  int row = blockIdx.x;            // 0..8191 : [stream][4096]
  int s = row >> 12, r = row & 4095;
  const float* __restrict__ src = s ? xb : xa;
  const float* __restrict__ gp = s ? gb : ga;
  const float* __restrict__ bp = s ? bb : ba;
  int tid = threadIdx.x;
  float4 v = ((const float4*)(src + (size_t)r * 768))[tid];
  float sum = v.x + v.y + v.z + v.w;
  float sq = v.x * v.x + v.y * v.y + v.z * v.z + v.w * v.w;
#pragma unroll
  for (int o = 32; o; o >>= 1) { sum += __shfl_down(sum, o); sq += __shfl_down(sq, o); }
  __shared__ float red[6];
  int wv = tid >> 6;
  if ((tid & 63) == 0) { red[wv] = sum; red[wv + 3] = sq; }
  __syncthreads();
  sum = red[0] + red[1] + red[2];
  sq = red[3] + red[4] + red[5];
  float mean = sum * (1.f / 768.f);
  float var = sq * (1.f / 768.f) - mean * mean;
  float rstd = rsqrtf(var + 1e-5f);
  float4 g4 = ((const float4*)gp)[tid], b4 = ((const float4*)bp)[tid];
  ushort4 u;
  u.x = bfb((v.x - mean) * rstd * g4.x + b4.x);
  u.y = bfb((v.y - mean) * rstd * g4.y + b4.y);
  u.z = bfb((v.z - mean) * rstd * g4.z + b4.z);
  u.w = bfb((v.w - mean) * rstd * g4.w + b4.w);
  *(ushort4*)&out[(size_t)row * 768 + tid * 4] = u;
}

// ---------------- GEMM: C[M,N] = A[M,K](bf16) @ B(=Wt[N][K] bf16), double-buffered 2-phase
// Block tile = 128 x (NT*32). Per wave 64 x (NT*16) = 4 x NT fragments.
// blockIdx.z = ck*2 + s (s = stream, ck = split-K chunk; ck=0 unless split).
// EPI: 0 = QKV scatter; 1 = fp32 res(+bias); 2 = gelu+bias -> bf16; 3 = raw bf16 partial (split-K)
template<int EPI, int NT>
__global__ __launch_bounds__(256) void gemm_k(const bf16* __restrict__ A0, const bf16* __restrict__ A1,
                                              const bf16* __restrict__ Bt0, const bf16* __restrict__ Bt1,
                                              void* __restrict__ C0, void* __restrict__ C1,
                                              const float* __restrict__ bias0, const float* __restrict__ bias1,
                                              const float* __restrict__ res0, const float* __restrict__ res1,
                                              int N, int K, int lda, int ldb) {
  int s = blockIdx.z & 1;
  int ck = blockIdx.z >> 1;
  const bf16* __restrict__ A = s ? A1 : A0;
  const bf16* __restrict__ Bt = s ? Bt1 : Bt0;
  const float* __restrict__ bias = s ? bias1 : bias0;
  const float* __restrict__ res = s ? res1 : res0;
  int m0 = blockIdx.x * 128, n0 = blockIdx.y * (NT * 32);
  int tid = threadIdx.x, lane = tid & 63, w = tid >> 6;
  int g = lane >> 4, li = lane & 15;
  int wm = w >> 1, wn = w & 1;
  __shared__ __align__(16) bf16 As[2][128 * 32];
  __shared__ __align__(16) bf16 Bs[2][NT * 32 * 32];
  f32x4 acc[4][NT];
  f32x4 zz = {0.f, 0.f, 0.f, 0.f};
#pragma unroll
  for (int i = 0; i < 4; i++)
#pragma unroll
    for (int j = 0; j < NT; j++) acc[i][j] = zz;

  const bf16* Ab = A + (size_t)m0 * lda + ck * K;
  const bf16* Bb = Bt + (size_t)n0 * ldb + ck * K;
  int sw = (g ^ (li & 3)) << 3;   // read-side XOR swizzle (k-unit ^ row&3)

  auto stage = [&](int buf, int k0) {
#pragma unroll
    for (int i = 0; i < 2; i++) {
      int unit = w * 64 + i * 256 + lane;
      int row = unit >> 2, up = unit & 3;
      int col = (up ^ (row & 3)) << 3;   // inverse swizzle on global source
      gload16(Ab + (size_t)row * lda + k0 + col, &As[buf][w * 512 + i * 2048]);
    }
#pragma unroll
    for (int i = 0; i < NT / 2; i++) {
      int unit = w * 64 + i * 256 + lane;
      int row = unit >> 2, up = unit & 3;
      int col = (up ^ (row & 3)) << 3;
      gload16(Bb + (size_t)row * ldb + k0 + col, &Bs[buf][w * 512 + i * 2048]);
    }
  };

  const int nt = K >> 5;
  stage(0, 0);
  int cur = 0;
  for (int t = 0; t < nt; ++t) {
    __syncthreads();                       // drains vmcnt(0): buf[cur] ready
    if (t + 1 < nt) stage(cur ^ 1, (t + 1) << 5);  // prefetch next in flight
    int4 af[4], bfr[NT];
#pragma unroll
    for (int mi = 0; mi < 4; mi++) af[mi] = *(const int4*)&As[cur][(wm * 64 + mi * 16 + li) * 32 + sw];
#pragma unroll
    for (int ni = 0; ni < NT; ni++) bfr[ni] = *(const int4*)&Bs[cur][(wn * (NT * 16) + ni * 16 + li) * 32 + sw];
#pragma unroll
    for (int mi = 0; mi < 4; mi++)
#pragma unroll
      for (int ni = 0; ni < NT; ni++) mfma16(af[mi], bfr[ni], acc[mi][ni]);
    cur ^= 1;
  }

  int mrow0 = m0 + wm * 64;
  int col0 = n0 + wn * (NT * 16);
  if constexpr (EPI == 0) {        // QKV scatter
    bf16* qkv = (bf16*)C0;
#pragma unroll
    for (int mi = 0; mi < 4; mi++) {
      int mr = mrow0 + mi * 16 + 4 * g;
      int b = mr >> 10, t = mr & 1023;
#pragma unroll
      for (int ni = 0; ni < NT; ni++) {
        int col = col0 + ni * 16 + li;
        int kk = col / 768; int hd = col - kk * 768; int h = hd >> 6; int dd = hd & 63;
        size_t base = ((size_t)(kk * 2 + s) * 48 + b * 12 + h) * 65536;
        f32x4 v = acc[mi][ni];
        if (kk == 2) {             // V stored transposed [dd][t]
          ushort4 u; u.x = bfb(v[0]); u.y = bfb(v[1]); u.z = bfb(v[2]); u.w = bfb(v[3]);
          *(ushort4*)&qkv[base + (size_t)dd * 1024 + t] = u;
        } else {
#pragma unroll
          for (int ri = 0; ri < 4; ri++)
            qkv[base + (size_t)(t + ri) * 64 + dd] = __float2bfloat16(v[ri]);
        }
      }
    }
  } else if constexpr (EPI == 1) { // fp32 out = res + acc (+bias)
    float* C = (float*)(s ? C1 : C0);
#pragma unroll
    for (int mi = 0; mi < 4; mi++) {
      int mr = mrow0 + mi * 16 + 4 * g;
#pragma unroll
      for (int ni = 0; ni < NT; ni++) {
        int col = col0 + ni * 16 + li;
        float bv = bias ? bias[col] : 0.f;
#pragma unroll
        for (int ri = 0; ri < 4; ri++)
          C[(size_t)(mr + ri) * N + col] = res[(size_t)(mr + ri) * N + col] + acc[mi][ni][ri] + bv;
      }
    }
  } else if constexpr (EPI == 2) { // gelu(acc+bias) -> bf16
    bf16* C = (bf16*)(s ? C1 : C0);
#pragma unroll
    for (int mi = 0; mi < 4; mi++) {
      int mr = mrow0 + mi * 16 + 4 * g;
#pragma unroll
      for (int ni = 0; ni < NT; ni++) {
        int col = col0 + ni * 16 + li;
        float bv = bias[col];
#pragma unroll
        for (int ri = 0; ri < 4; ri++)
          C[(size_t)(mr + ri) * N + col] = __float2bfloat16(gelu_f(acc[mi][ni][ri] + bv));
      }
    }
  } else {                         // EPI==3: raw bf16 partial store P[ck][s][4096][N]
    bf16* C = (bf16*)C0 + (size_t)(ck * 2 + s) * 4096 * N;
#pragma unroll
    for (int mi = 0; mi < 4; mi++) {
      int mr = mrow0 + mi * 16 + 4 * g;
#pragma unroll
      for (int ni = 0; ni < NT; ni++) {
        int col = col0 + ni * 16 + li;
#pragma unroll
        for (int ri = 0; ri < 4; ri++)
          C[(size_t)(mr + ri) * N + col] = __float2bfloat16(acc[mi][ni][ri]);
      }
    }
  }
}

// ---------------- split-K combine for MLP2: OUT = X2res + bias + P[0] + P[1] (fp32 out)
__global__ __launch_bounds__(192) void mlp2c(const bf16* __restrict__ P, const float* __restrict__ res,
                                             const float* __restrict__ ba, const float* __restrict__ bb,
                                             float* __restrict__ out) {
  int row = blockIdx.x;            // [stream][4096]
  int s = row >> 12, r = row & 4095;
  const float* __restrict__ bp = s ? bb : ba;
  int tid = threadIdx.x;
  float4 rv = ((const float4*)(res + (size_t)row * 768))[tid];
  float4 bv = ((const float4*)bp)[tid];
  ushort4 p0 = ((const ushort4*)(P + ((size_t)s * 4096 + r) * 768))[tid];
  ushort4 p1 = ((const ushort4*)(P + ((size_t)(2 + s) * 4096 + r) * 768))[tid];
  float4 o;
  o.x = rv.x + bv.x + b2f(p0.x) + b2f(p1.x);
  o.y = rv.y + bv.y + b2f(p0.y) + b2f(p1.y);
  o.z = rv.z + bv.z + b2f(p0.z) + b2f(p1.z);
  o.w = rv.w + bv.w + b2f(p0.w) + b2f(p1.w);
  ((float4*)(out + (size_t)row * 768))[tid] = o;
}

// ---------------- flash attention, LDS-staged K/V, 8 waves/block x 16 q-rows each.
// STATIC-MAX softmax: P = exp2((s - M0)*C2), constant M0 cancels in O/l.
// q,k [bh][1024][64] bf16, v [bh][64][1024] bf16 (V^T). out bf16 [stream][4096][768].
// S^T = mfma(K,Q): lane owns q-col. O^T = mfma(V,P). 512 thr, 48KB LDS -> 3 blk/CU, 24 waves/CU.
__global__ __launch_bounds__(512, 6) void attn_k(const bf16* __restrict__ qkv, bf16* __restrict__ out, int cross) {
  // XCD-grouped flat mapping: all 8 q-tiles of one (bh,stream) land on one XCD.
  int f = blockIdx.x;
  int qt = (f >> 3) & 7;
  int c = ((f >> 6) << 3) | (f & 7);   // 0..95
  int so = (c >= 48) ? 1 : 0;
  int bh = c - so * 48;
  int qs = cross ? 1 - so : so;
  const bf16* __restrict__ qp = qkv + ((size_t)qs * 48 + bh) * 65536;
  const bf16* __restrict__ kp = qkv + ((size_t)(2 + so) * 48 + bh) * 65536;
  const bf16* __restrict__ vp = qkv + ((size_t)(4 + so) * 48 + bh) * 65536;
  int tid = threadIdx.x, lane = tid & 63, w = tid >> 6, g = lane >> 4, li = lane & 15;
  __shared__ __align__(16) bf16 Ks[2][64 * 64];   // [t][d], unit u at u^(t&7)
  __shared__ __align__(16) bf16 Vs[2][64 * 64];   // [d][t], unit u at u^(d&7)
  __shared__ __align__(16) bf16 Ps[8][16 * 64];   // per-wave P tile [16q][64t]
  bf16* ps = Ps[w];
  int qr0 = qt * 128 + w * 16;                    // 8 waves x 16 q-rows = 128
  int4 qf[2];
#pragma unroll
  for (int ks = 0; ks < 2; ks++)
    qf[ks] = *(const int4*)(qp + (size_t)(qr0 + li) * 64 + ks * 32 + 8 * g);
  f32x4 o_acc[4];
  float l_run = 0.f;
  f32x4 zz = {0.f, 0.f, 0.f, 0.f};
#pragma unroll
  for (int dj = 0; dj < 4; dj++) o_acc[dj] = zz;
  const float C2 = 0.18033688011112042f; // (1/8)*log2(e)
  const float MB = 12.0f * C2;           // static max offset (in exp2 domain)
  const int xsw = (li & 7);

  // stage K-tile + V-tile for kt into buf: 512 16B-units each, 1 unit per thread.
  // gload16 LDS dest = wave-uniform base + lane*16; source pre-swizzled (rule 21).
  auto stage = [&](int buf, int kt) {
    int r = tid >> 3, u = tid & 7;       // row, 16B-unit within row
    int su = (u ^ (r & 7)) << 3;         // swizzled element offset
    gload16(kp + (size_t)(kt * 64 + r) * 64 + su, &Ks[buf][(w * 64) * 8]);
    gload16(vp + (size_t)r * 1024 + kt * 64 + su, &Vs[buf][(w * 64) * 8]);
  };

  stage(0, 0);
  int cur = 0;
#pragma unroll 2
  for (int kt = 0; kt < 16; ++kt) {
    __syncthreads();                        // drains vmcnt(0): buf[cur] ready; prev readers done
    if (kt < 15) stage(cur ^ 1, kt + 1);    // async prefetch, hidden under compute
    // --- QK^T from LDS (S^T tile rows t, cols q)
    f32x4 sacc[4];
#pragma unroll
    for (int nj = 0; nj < 4; nj++) sacc[nj] = zz;
    __builtin_amdgcn_s_setprio(1);
#pragma unroll
    for (int nj = 0; nj < 4; nj++) {
      int trow = nj * 16 + li;
      int4 kf0 = *(const int4*)&Ks[cur][trow * 64 + ((g ^ (trow & 7)) << 3)];
      int4 kf1 = *(const int4*)&Ks[cur][trow * 64 + (((4 + g) ^ (trow & 7)) << 3)];
      mfma16(kf0, qf[0], sacc[nj]);
      mfma16(kf1, qf[1], sacc[nj]);
    }
    __builtin_amdgcn_s_setprio(0);
    // --- static-max softmax: P = exp2(s*C2 - MB); no max tracking, no rescale
    {
      float rs = 0.f;
#pragma unroll
      for (int nj = 0; nj < 4; nj++) {
        float p0 = exp2f(fmaf(sacc[nj][0], C2, -MB));
        float p1 = exp2f(fmaf(sacc[nj][1], C2, -MB));
        float p2 = exp2f(fmaf(sacc[nj][2], C2, -MB));
        float p3 = exp2f(fmaf(sacc[nj][3], C2, -MB));
        rs += (p0 + p1) + (p2 + p3);
        int2 u2; u2.x = cvtpk(p0, p1); u2.y = cvtpk(p2, p3);
        *(int2*)&ps[li * 64 + (((2 * nj + (g >> 1)) ^ xsw) << 3) + ((g & 1) << 2)] = u2;
      }
      l_run += rs;                        // lane-partial; reduced once at the end
    }
    // --- O^T += V^T x P from LDS
    __builtin_amdgcn_s_setprio(1);
#pragma unroll
    for (int ks2 = 0; ks2 < 2; ks2++) {
      int4 pa = *(const int4*)&ps[li * 64 + (((4 * ks2 + g) ^ xsw) << 3)];
#pragma unroll
      for (int dj = 0; dj < 4; dj++) {
        int drow = dj * 16 + li;
        int4 vf = *(const int4*)&Vs[cur][drow * 64 + ((((ks2 << 2) + g) ^ (drow & 7)) << 3)];
        mfma16(vf, pa, o_acc[dj]);
      }
    }
    __builtin_amdgcn_s_setprio(0);
    cur ^= 1;
  }
  int b = bh / 12, h = bh - (bh / 12) * 12;
  float lt = l_run;
  lt += __shfl_xor(lt, 16);
  lt += __shfl_xor(lt, 32);
  float inv = 1.f / lt;
  int tq = qr0 + li;
  size_t rowbase = ((size_t)so * 4096 + (size_t)b * 1024 + tq) * 768;
#pragma unroll
  for (int dj = 0; dj < 4; dj++) {
    ushort4 u;
    u.x = bfb(o_acc[dj][0] * inv); u.y = bfb(o_acc[dj][1] * inv);
    u.z = bfb(o_acc[dj][2] * inv); u.w = bfb(o_acc[dj][3] * inv);
    *(ushort4*)&out[rowbase + h * 64 + dj * 16 + 4 * g] = u;
  }
}

extern "C" void kernel_launch(void* const* d_in, const int* in_sizes, int n_in,
                              void* d_out, int out_size, void* d_ws, size_t ws_size,
                              hipStream_t stream) {
  const float* x_in = (const float*)d_in[0];
  const float* y_in = (const float*)d_in[1];
  const float* w_qkv_a = (const float*)d_in[2];
  const float* w_out_a = (const float*)d_in[3];
  const float* w_qkv_b = (const float*)d_in[4];
  const float* w_out_b = (const float*)d_in[5];
  const float* cw_qkv_a = (const float*)d_in[6];
  const float* cw_out_a = (const float*)d_in[7];
  const float* cw_qkv_b = (const float*)d_in[8];
  const float* cw_out_b = (const float*)d_in[9];
  const float* w1a = (const float*)d_in[10]; const float* b1a = (const float*)d_in[11];
  const float* w2a = (const float*)d_in[12]; const float* b2a = (const float*)d_in[13];
  const float* w1b = (const float*)d_in[14]; const float* b1b = (const float*)d_in[15];
  const float* w2b = (const float*)d_in[16]; const float* b2b = (const float*)d_in[17];
  const float *lng[6], *lnb[6];
  for (int i = 0; i < 6; i++) { lng[i] = (const float*)d_in[18 + 2 * i]; lnb[i] = (const float*)d_in[19 + 2 * i]; }

  char* ws = (char*)d_ws;
  bf16* WQKV = (bf16*)ws;                      // 4 x [2304][768] bf16 (transposed+permuted)
  bf16* WOUT = (bf16*)(ws + 14155776);         // 4 x [768][768]
  bf16* W1 = (bf16*)(ws + 18874368);           // 2 x [3072][768]
  bf16* W2 = (bf16*)(ws + 28311552);           // 2 x [768][3072]
  bf16* XN = (bf16*)(ws + 37748736);           // [2][4096][768] normed bf16
  bf16* QKV = (bf16*)(ws + 50331648);          // [3][2][48][1024][64]
  bf16* AO = (bf16*)(ws + 88080384);           // [2][4096][768]
  bf16* MLPH = (bf16*)(ws + 50331648);         // [2][4096][3072] (overlays QKV+AO in stage 3)
  float* X1 = (float*)(ws + 100663296);        // [2][4096][768] fp32
  float* X2 = (float*)(ws + 125829120);
  bf16* Pbuf = (bf16*)(ws + 100663296);        // split-K partials [2ck][2s][4096][768] bf16 (X1 slot, dead in MLP stage)
  float* OUT = (float*)d_out;

  dim3 tb(32, 8);
  wconv<true><<<dim3(72, 24, 4), tb, 0, stream>>>(w_qkv_a, w_qkv_b, cw_qkv_a, cw_qkv_b,
      WQKV, WQKV + 1769472, WQKV + 2 * 1769472, WQKV + 3 * 1769472, 768, 2304);
  wconv<false><<<dim3(24, 24, 4), tb, 0, stream>>>(w_out_a, w_out_b, cw_out_a, cw_out_b,
      WOUT, WOUT + 589824, WOUT + 2 * 589824, WOUT + 3 * 589824, 768, 768);
  wconv<false><<<dim3(96, 24, 2), tb, 0, stream>>>(w1a, w1b, nullptr, nullptr,
      W1, W1 + 2359296, nullptr, nullptr, 768, 3072);
  wconv<false><<<dim3(24, 96, 2), tb, 0, stream>>>(w2a, w2b, nullptr, nullptr,
      W2, W2 + 2359296, nullptr, nullptr, 3072, 768);

  // ---- self-attention stage
  ln2<<<8192, 192, 0, stream>>>(x_in, y_in, lng[0], lnb[0], lng[3], lnb[3], XN);
  gemm_k<0, 4><<<dim3(32, 18, 2), 256, 0, stream>>>(XN, XN + 3145728, WQKV, WQKV + 1769472,
      QKV, nullptr, nullptr, nullptr, nullptr, nullptr, 2304, 768, 768, 768);
  attn_k<<<dim3(768, 1, 1), 512, 0, stream>>>(QKV, AO, 0);
  gemm_k<1, 4><<<dim3(32, 6, 2), 256, 0, stream>>>(AO, AO + 3145728, WOUT, WOUT + 589824,
      X1, X1 + 3145728, nullptr, nullptr, x_in, y_in, 768, 768, 768, 768);
  // ---- cross-attention stage
  ln2<<<8192, 192, 0, stream>>>(X1, X1 + 3145728, lng[1], lnb[1], lng[4], lnb[4], XN);
  gemm_k<0, 4><<<dim3(32, 18, 2), 256, 0, stream>>>(XN, XN + 3145728, WQKV + 2 * 1769472, WQKV + 3 * 1769472,
      QKV, nullptr, nullptr, nullptr, nullptr, nullptr, 2304, 768, 768, 768);
  attn_k<<<dim3(768, 1, 1), 512, 0, stream>>>(QKV, AO, 1);
  gemm_k<1, 4><<<dim3(32, 6, 2), 256, 0, stream>>>(AO, AO + 3145728, WOUT + 2 * 589824, WOUT + 3 * 589824,
      X2, X2 + 3145728, nullptr, nullptr, X1, X1 + 3145728, 768, 768, 768, 768);
  // ---- MLP stage
  ln2<<<8192, 192, 0, stream>>>(X2, X2 + 3145728, lng[2], lnb[2], lng[5], lnb[5], XN);
  // MLP1: 128x256 tile (NT=8) — 2x MFMA per barrier; grid 32x12x2 = 768 blocks
  gemm_k<2, 8><<<dim3(32, 12, 2), 256, 0, stream>>>(XN, XN + 3145728, W1, W1 + 2359296,
      MLPH, MLPH + 12582912, b1a, b1b, nullptr, nullptr, 3072, 768, 768, 768);
  // MLP2 split-K=2: z = ck*2 + s, each chunk K=1536 (lda/ldb = full 3072)
  gemm_k<3, 4><<<dim3(32, 6, 4), 256, 0, stream>>>(MLPH, MLPH + 12582912, W2, W2 + 2359296,
      Pbuf, nullptr, nullptr, nullptr, nullptr, nullptr, 768, 1536, 3072, 3072);
  mlp2c<<<8192, 192, 0, stream>>>(Pbuf, X2, b2a, b2b, OUT);
}

// Round 20
// 415.641 us; speedup vs baseline: 1.0672x; 1.0672x over previous
//
#include <hip/hip_runtime.h>
#include <hip/hip_bf16.h>

using bf16 = __hip_bfloat16;
typedef __bf16 bf16x8 __attribute__((ext_vector_type(8)));
typedef float f32x4 __attribute__((ext_vector_type(4)));

#define DEV __device__ __forceinline__

// async global->LDS, 16B per lane. LDS dest = wave-uniform base + lane*16.
DEV void gload16(const void* g, void* l) {
  __builtin_amdgcn_global_load_lds((__attribute__((address_space(1))) void*)(g),
                                   (__attribute__((address_space(3))) void*)(l), 16, 0, 0);
}

DEV void mfma16(int4 a, int4 b, f32x4& c) {
  c = __builtin_amdgcn_mfma_f32_16x16x32_bf16(
      __builtin_bit_cast(bf16x8, a), __builtin_bit_cast(bf16x8, b), c, 0, 0, 0);
}

DEV unsigned short bfb(float x) { return __builtin_bit_cast(unsigned short, __float2bfloat16(x)); }

DEV int cvtpk(float lo, float hi) {
  int r;
  asm("v_cvt_pk_bf16_f32 %0, %1, %2" : "=v"(r) : "v"(lo), "v"(hi));
  return r;
}

DEV float b2f(unsigned short u) {
  unsigned int v = (unsigned int)u << 16;
  return __builtin_bit_cast(float, v);
}

// fast exact-erf GELU (A&S 7.1.26, |err|<=2e-7 — far below bf16 rounding)
DEV float gelu_f(float h) {
  float xr = h * 0.70710678118f;
  float ax = fabsf(xr);
  float t = __builtin_amdgcn_rcpf(fmaf(0.3275911f, ax, 1.f));
  float poly = fmaf(fmaf(fmaf(fmaf(1.061405429f, t, -1.453152027f), t, 1.421413741f),
                         t, -0.284496736f), t, 0.254829592f) * t;
  float e = __expf(-xr * xr);
  float erfv = copysignf(1.f - poly * e, xr);
  return 0.5f * h * (1.f + erfv);
}

// ---------------- weight convert: fp32 [K][N] -> bf16 W^T [N][K] (optionally QKV-permuted rows)
template<bool PERM>
__global__ __launch_bounds__(256) void wconv(const float* __restrict__ s0, const float* __restrict__ s1,
                                             const float* __restrict__ s2, const float* __restrict__ s3,
                                             bf16* d0, bf16* d1, bf16* d2, bf16* d3, int K, int N) {
  const float* S[4] = {s0, s1, s2, s3};
  bf16* Dd[4] = {d0, d1, d2, d3};
  const float* __restrict__ src = S[blockIdx.z];
  bf16* __restrict__ dst = Dd[blockIdx.z];
  __shared__ float tile[32][33];
  int tx = threadIdx.x, ty = threadIdx.y;
  int n0 = blockIdx.x * 32, k0 = blockIdx.y * 32;
#pragma unroll
  for (int i = 0; i < 4; i++) tile[ty + 8 * i][tx] = src[(size_t)(k0 + ty + 8 * i) * N + n0 + tx];
  __syncthreads();
#pragma unroll
  for (int i = 0; i < 4; i++) {
    int n = n0 + ty + 8 * i;
    int np;
    if (PERM) { // orig col n = dd*36 + kk*12 + h  ->  np = kk*768 + h*64 + dd
      int dd = n / 36; int r = n - dd * 36; int kk = r / 12; int h = r - kk * 12;
      np = kk * 768 + h * 64 + dd;
    } else np = n;
    dst[(size_t)np * K + k0 + tx] = __float2bfloat16(tile[tx][ty + 8 * i]);
  }
}

// ---------------- LayerNorm (fp32 in) -> bf16 out, both streams in one launch
__global__ __launch_bounds__(192) void ln2(const float* __restrict__ xa, const float* __restrict__ xb,
                                           const float* __restrict__ ga, const float* __restrict__ ba,
                                           const float* __restrict__ gb, const float* __restrict__ bb,
                                           bf16* __restrict__ out) {
  int row = blockIdx.x;            // 0..8191 : [stream][4096]
  int s = row >> 12, r = row & 4095;
  const float* __restrict__ src = s ? xb : xa;
  const float* __restrict__ gp = s ? gb : ga;
  const float* __restrict__ bp = s ? bb : ba;
  int tid = threadIdx.x;
  float4 v = ((const float4*)(src + (size_t)r * 768))[tid];
  float sum = v.x + v.y + v.z + v.w;
  float sq = v.x * v.x + v.y * v.y + v.z * v.z + v.w * v.w;
#pragma unroll
  for (int o = 32; o; o >>= 1) { sum += __shfl_down(sum, o); sq += __shfl_down(sq, o); }
  __shared__ float red[6];
  int wv = tid >> 6;
  if ((tid & 63) == 0) { red[wv] = sum; red[wv + 3] = sq; }
  __syncthreads();
  sum = red[0] + red[1] + red[2];
  sq = red[3] + red[4] + red[5];
  float mean = sum * (1.f / 768.f);
  float var = sq * (1.f / 768.f) - mean * mean;
  float rstd = rsqrtf(var + 1e-5f);
  float4 g4 = ((const float4*)gp)[tid], b4 = ((const float4*)bp)[tid];
  ushort4 u;
  u.x = bfb((v.x - mean) * rstd * g4.x + b4.x);
  u.y = bfb((v.y - mean) * rstd * g4.y + b4.y);
  u.z = bfb((v.z - mean) * rstd * g4.z + b4.z);
  u.w = bfb((v.w - mean) * rstd * g4.w + b4.w);
  *(ushort4*)&out[(size_t)row * 768 + tid * 4] = u;
}

// ---------------- GEMM: C[M,N] = A[M,K](bf16) @ B(=Wt[N][K] bf16), double-buffered 2-phase
// blockIdx.z = ck*2 + s (s = stream, ck = split-K chunk; ck=0 unless split).
// EPI: 0 = QKV scatter; 1 = fp32 res(+bias); 2 = gelu+bias -> bf16; 3 = raw bf16 partial (split-K)
template<int EPI>
__global__ __launch_bounds__(256) void gemm_k(const bf16* __restrict__ A0, const bf16* __restrict__ A1,
                                              const bf16* __restrict__ Bt0, const bf16* __restrict__ Bt1,
                                              void* __restrict__ C0, void* __restrict__ C1,
                                              const float* __restrict__ bias0, const float* __restrict__ bias1,
                                              const float* __restrict__ res0, const float* __restrict__ res1,
                                              int N, int K, int lda, int ldb) {
  int s = blockIdx.z & 1;
  int ck = blockIdx.z >> 1;
  const bf16* __restrict__ A = s ? A1 : A0;
  const bf16* __restrict__ Bt = s ? Bt1 : Bt0;
  const float* __restrict__ bias = s ? bias1 : bias0;
  const float* __restrict__ res = s ? res1 : res0;
  int m0 = blockIdx.x * 128, n0 = blockIdx.y * 128;
  int tid = threadIdx.x, lane = tid & 63, w = tid >> 6;
  int g = lane >> 4, li = lane & 15;
  int wm = w >> 1, wn = w & 1;
  __shared__ __align__(16) bf16 As[2][128 * 32];
  __shared__ __align__(16) bf16 Bs[2][128 * 32];
  f32x4 acc[4][4];
  f32x4 zz = {0.f, 0.f, 0.f, 0.f};
#pragma unroll
  for (int i = 0; i < 4; i++)
#pragma unroll
    for (int j = 0; j < 4; j++) acc[i][j] = zz;

  const bf16* Ab = A + (size_t)m0 * lda + ck * K;
  const bf16* Bb = Bt + (size_t)n0 * ldb + ck * K;
  int sw = (g ^ (li & 3)) << 3;   // read-side XOR swizzle (k-unit ^ row&3)

  auto stage = [&](int buf, int k0) {
#pragma unroll
    for (int i = 0; i < 2; i++) {
      int unit = w * 64 + i * 256 + lane;
      int row = unit >> 2, up = unit & 3;
      int col = (up ^ (row & 3)) << 3;   // inverse swizzle on global source
      gload16(Ab + (size_t)row * lda + k0 + col, &As[buf][w * 512 + i * 2048]);
      gload16(Bb + (size_t)row * ldb + k0 + col, &Bs[buf][w * 512 + i * 2048]);
    }
  };

  const int nt = K >> 5;
  stage(0, 0);
  int cur = 0;
  for (int t = 0; t < nt; ++t) {
    __syncthreads();                       // drains vmcnt(0): buf[cur] ready
    if (t + 1 < nt) stage(cur ^ 1, (t + 1) << 5);  // prefetch next in flight
    int4 af[4], bfr[4];
#pragma unroll
    for (int mi = 0; mi < 4; mi++) af[mi] = *(const int4*)&As[cur][(wm * 64 + mi * 16 + li) * 32 + sw];
#pragma unroll
    for (int ni = 0; ni < 4; ni++) bfr[ni] = *(const int4*)&Bs[cur][(wn * 64 + ni * 16 + li) * 32 + sw];
#pragma unroll
    for (int mi = 0; mi < 4; mi++)
#pragma unroll
      for (int ni = 0; ni < 4; ni++) mfma16(af[mi], bfr[ni], acc[mi][ni]);
    cur ^= 1;
  }

  int mrow0 = m0 + wm * 64;
  int col0 = n0 + wn * 64;
  if constexpr (EPI == 0) {        // QKV scatter
    bf16* qkv = (bf16*)C0;
#pragma unroll
    for (int mi = 0; mi < 4; mi++) {
      int mr = mrow0 + mi * 16 + 4 * g;
      int b = mr >> 10, t = mr & 1023;
#pragma unroll
      for (int ni = 0; ni < 4; ni++) {
        int col = col0 + ni * 16 + li;
        int kk = col / 768; int hd = col - kk * 768; int h = hd >> 6; int dd = hd & 63;
        size_t base = ((size_t)(kk * 2 + s) * 48 + b * 12 + h) * 65536;
        f32x4 v = acc[mi][ni];
        if (kk == 2) {             // V stored transposed [dd][t]
          ushort4 u; u.x = bfb(v[0]); u.y = bfb(v[1]); u.z = bfb(v[2]); u.w = bfb(v[3]);
          *(ushort4*)&qkv[base + (size_t)dd * 1024 + t] = u;
        } else {
#pragma unroll
          for (int ri = 0; ri < 4; ri++)
            qkv[base + (size_t)(t + ri) * 64 + dd] = __float2bfloat16(v[ri]);
        }
      }
    }
  } else if constexpr (EPI == 1) { // fp32 out = res + acc (+bias)
    float* C = (float*)(s ? C1 : C0);
#pragma unroll
    for (int mi = 0; mi < 4; mi++) {
      int mr = mrow0 + mi * 16 + 4 * g;
#pragma unroll
      for (int ni = 0; ni < 4; ni++) {
        int col = col0 + ni * 16 + li;
        float bv = bias ? bias[col] : 0.f;
#pragma unroll
        for (int ri = 0; ri < 4; ri++)
          C[(size_t)(mr + ri) * N + col] = res[(size_t)(mr + ri) * N + col] + acc[mi][ni][ri] + bv;
      }
    }
  } else if constexpr (EPI == 2) { // gelu(acc+bias) -> bf16
    bf16* C = (bf16*)(s ? C1 : C0);
#pragma unroll
    for (int mi = 0; mi < 4; mi++) {
      int mr = mrow0 + mi * 16 + 4 * g;
#pragma unroll
      for (int ni = 0; ni < 4; ni++) {
        int col = col0 + ni * 16 + li;
        float bv = bias[col];
#pragma unroll
        for (int ri = 0; ri < 4; ri++)
          C[(size_t)(mr + ri) * N + col] = __float2bfloat16(gelu_f(acc[mi][ni][ri] + bv));
      }
    }
  } else {                         // EPI==3: raw bf16 partial store P[ck][s][4096][N]
    bf16* C = (bf16*)C0 + (size_t)(ck * 2 + s) * 4096 * N;
#pragma unroll
    for (int mi = 0; mi < 4; mi++) {
      int mr = mrow0 + mi * 16 + 4 * g;
#pragma unroll
      for (int ni = 0; ni < 4; ni++) {
        int col = col0 + ni * 16 + li;
#pragma unroll
        for (int ri = 0; ri < 4; ri++)
          C[(size_t)(mr + ri) * N + col] = __float2bfloat16(acc[mi][ni][ri]);
      }
    }
  }
}

// ---------------- split-K combine for MLP2: OUT = X2res + bias + P[0] + P[1] (fp32 out)
__global__ __launch_bounds__(192) void mlp2c(const bf16* __restrict__ P, const float* __restrict__ res,
                                             const float* __restrict__ ba, const float* __restrict__ bb,
                                             float* __restrict__ out) {
  int row = blockIdx.x;            // [stream][4096]
  int s = row >> 12, r = row & 4095;
  const float* __restrict__ bp = s ? bb : ba;
  int tid = threadIdx.x;
  float4 rv = ((const float4*)(res + (size_t)row * 768))[tid];
  float4 bv = ((const float4*)bp)[tid];
  ushort4 p0 = ((const ushort4*)(P + ((size_t)s * 4096 + r) * 768))[tid];
  ushort4 p1 = ((const ushort4*)(P + ((size_t)(2 + s) * 4096 + r) * 768))[tid];
  float4 o;
  o.x = rv.x + bv.x + b2f(p0.x) + b2f(p1.x);
  o.y = rv.y + bv.y + b2f(p0.y) + b2f(p1.y);
  o.z = rv.z + bv.z + b2f(p0.z) + b2f(p1.z);
  o.w = rv.w + bv.w + b2f(p0.w) + b2f(p1.w);
  ((float4*)(out + (size_t)row * 768))[tid] = o;
}

// ---------------- flash attention, LDS-staged K/V, 8 waves/block x 16 q-rows each.
// STATIC-MAX softmax: P = exp2((s - M0)*C2), constant M0 cancels in O/l.
// q,k [bh][1024][64] bf16, v [bh][64][1024] bf16 (V^T). out bf16 [stream][4096][768].
// S^T = mfma(K,Q): lane owns q-col. O^T = mfma(V,P). 512 thr, 48KB LDS -> 3 blk/CU, 24 waves/CU.
__global__ __launch_bounds__(512, 6) void attn_k(const bf16* __restrict__ qkv, bf16* __restrict__ out, int cross) {
  // XCD-grouped flat mapping: all 8 q-tiles of one (bh,stream) land on one XCD.
  int f = blockIdx.x;
  int qt = (f >> 3) & 7;
  int c = ((f >> 6) << 3) | (f & 7);   // 0..95
  int so = (c >= 48) ? 1 : 0;
  int bh = c - so * 48;
  int qs = cross ? 1 - so : so;
  const bf16* __restrict__ qp = qkv + ((size_t)qs * 48 + bh) * 65536;
  const bf16* __restrict__ kp = qkv + ((size_t)(2 + so) * 48 + bh) * 65536;
  const bf16* __restrict__ vp = qkv + ((size_t)(4 + so) * 48 + bh) * 65536;
  int tid = threadIdx.x, lane = tid & 63, w = tid >> 6, g = lane >> 4, li = lane & 15;
  __shared__ __align__(16) bf16 Ks[2][64 * 64];   // [t][d], unit u at u^(t&7)
  __shared__ __align__(16) bf16 Vs[2][64 * 64];   // [d][t], unit u at u^(d&7)
  __shared__ __align__(16) bf16 Ps[8][16 * 64];   // per-wave P tile [16q][64t]
  bf16* ps = Ps[w];
  int qr0 = qt * 128 + w * 16;                    // 8 waves x 16 q-rows = 128
  int4 qf[2];
#pragma unroll
  for (int ks = 0; ks < 2; ks++)
    qf[ks] = *(const int4*)(qp + (size_t)(qr0 + li) * 64 + ks * 32 + 8 * g);
  f32x4 o_acc[4];
  float l_run = 0.f;
  f32x4 zz = {0.f, 0.f, 0.f, 0.f};
#pragma unroll
  for (int dj = 0; dj < 4; dj++) o_acc[dj] = zz;
  const float C2 = 0.18033688011112042f; // (1/8)*log2(e)
  const float MB = 12.0f * C2;           // static max offset (in exp2 domain)
  const int xsw = (li & 7);

  // stage K-tile + V-tile for kt into buf: 512 16B-units each, 1 unit per thread.
  // gload16 LDS dest = wave-uniform base + lane*16; source pre-swizzled (rule 21).
  auto stage = [&](int buf, int kt) {
    int r = tid >> 3, u = tid & 7;       // row, 16B-unit within row
    int su = (u ^ (r & 7)) << 3;         // swizzled element offset
    gload16(kp + (size_t)(kt * 64 + r) * 64 + su, &Ks[buf][(w * 64) * 8]);
    gload16(vp + (size_t)r * 1024 + kt * 64 + su, &Vs[buf][(w * 64) * 8]);
  };

  stage(0, 0);
  int cur = 0;
#pragma unroll 2
  for (int kt = 0; kt < 16; ++kt) {
    __syncthreads();                        // drains vmcnt(0): buf[cur] ready; prev readers done
    if (kt < 15) stage(cur ^ 1, kt + 1);    // async prefetch, hidden under compute
    // --- QK^T from LDS (S^T tile rows t, cols q)
    f32x4 sacc[4];
#pragma unroll
    for (int nj = 0; nj < 4; nj++) sacc[nj] = zz;
    __builtin_amdgcn_s_setprio(1);
#pragma unroll
    for (int nj = 0; nj < 4; nj++) {
      int trow = nj * 16 + li;
      int4 kf0 = *(const int4*)&Ks[cur][trow * 64 + ((g ^ (trow & 7)) << 3)];
      int4 kf1 = *(const int4*)&Ks[cur][trow * 64 + (((4 + g) ^ (trow & 7)) << 3)];
      mfma16(kf0, qf[0], sacc[nj]);
      mfma16(kf1, qf[1], sacc[nj]);
    }
    __builtin_amdgcn_s_setprio(0);
    // --- static-max softmax: P = exp2(s*C2 - MB); no max tracking, no rescale
    {
      float rs = 0.f;
#pragma unroll
      for (int nj = 0; nj < 4; nj++) {
        float p0 = exp2f(fmaf(sacc[nj][0], C2, -MB));
        float p1 = exp2f(fmaf(sacc[nj][1], C2, -MB));
        float p2 = exp2f(fmaf(sacc[nj][2], C2, -MB));
        float p3 = exp2f(fmaf(sacc[nj][3], C2, -MB));
        rs += (p0 + p1) + (p2 + p3);
        int2 u2; u2.x = cvtpk(p0, p1); u2.y = cvtpk(p2, p3);
        *(int2*)&ps[li * 64 + (((2 * nj + (g >> 1)) ^ xsw) << 3) + ((g & 1) << 2)] = u2;
      }
      l_run += rs;                        // lane-partial; reduced once at the end
    }
    // --- O^T += V^T x P from LDS
    __builtin_amdgcn_s_setprio(1);
#pragma unroll
    for (int ks2 = 0; ks2 < 2; ks2++) {
      int4 pa = *(const int4*)&ps[li * 64 + (((4 * ks2 + g) ^ xsw) << 3)];
#pragma unroll
      for (int dj = 0; dj < 4; dj++) {
        int drow = dj * 16 + li;
        int4 vf = *(const int4*)&Vs[cur][drow * 64 + ((((ks2 << 2) + g) ^ (drow & 7)) << 3)];
        mfma16(vf, pa, o_acc[dj]);
      }
    }
    __builtin_amdgcn_s_setprio(0);
    cur ^= 1;
  }
  int b = bh / 12, h = bh - (bh / 12) * 12;
  float lt = l_run;
  lt += __shfl_xor(lt, 16);
  lt += __shfl_xor(lt, 32);
  float inv = 1.f / lt;
  int tq = qr0 + li;
  size_t rowbase = ((size_t)so * 4096 + (size_t)b * 1024 + tq) * 768;
#pragma unroll
  for (int dj = 0; dj < 4; dj++) {
    ushort4 u;
    u.x = bfb(o_acc[dj][0] * inv); u.y = bfb(o_acc[dj][1] * inv);
    u.z = bfb(o_acc[dj][2] * inv); u.w = bfb(o_acc[dj][3] * inv);
    *(ushort4*)&out[rowbase + h * 64 + dj * 16 + 4 * g] = u;
  }
}

extern "C" void kernel_launch(void* const* d_in, const int* in_sizes, int n_in,
                              void* d_out, int out_size, void* d_ws, size_t ws_size,
                              hipStream_t stream) {
  const float* x_in = (const float*)d_in[0];
  const float* y_in = (const float*)d_in[1];
  const float* w_qkv_a = (const float*)d_in[2];
  const float* w_out_a = (const float*)d_in[3];
  const float* w_qkv_b = (const float*)d_in[4];
  const float* w_out_b = (const float*)d_in[5];
  const float* cw_qkv_a = (const float*)d_in[6];
  const float* cw_out_a = (const float*)d_in[7];
  const float* cw_qkv_b = (const float*)d_in[8];
  const float* cw_out_b = (const float*)d_in[9];
  const float* w1a = (const float*)d_in[10]; const float* b1a = (const float*)d_in[11];
  const float* w2a = (const float*)d_in[12]; const float* b2a = (const float*)d_in[13];
  const float* w1b = (const float*)d_in[14]; const float* b1b = (const float*)d_in[15];
  const float* w2b = (const float*)d_in[16]; const float* b2b = (const float*)d_in[17];
  const float *lng[6], *lnb[6];
  for (int i = 0; i < 6; i++) { lng[i] = (const float*)d_in[18 + 2 * i]; lnb[i] = (const float*)d_in[19 + 2 * i]; }

  char* ws = (char*)d_ws;
  bf16* WQKV = (bf16*)ws;                      // 4 x [2304][768] bf16 (transposed+permuted)
  bf16* WOUT = (bf16*)(ws + 14155776);         // 4 x [768][768]
  bf16* W1 = (bf16*)(ws + 18874368);           // 2 x [3072][768]
  bf16* W2 = (bf16*)(ws + 28311552);           // 2 x [768][3072]
  bf16* XN = (bf16*)(ws + 37748736);           // [2][4096][768] normed bf16
  bf16* QKV = (bf16*)(ws + 50331648);          // [3][2][48][1024][64]
  bf16* AO = (bf16*)(ws + 88080384);           // [2][4096][768]
  bf16* MLPH = (bf16*)(ws + 50331648);         // [2][4096][3072] (overlays QKV+AO in stage 3)
  float* X1 = (float*)(ws + 100663296);        // [2][4096][768] fp32
  float* X2 = (float*)(ws + 125829120);
  bf16* Pbuf = (bf16*)(ws + 100663296);        // split-K partials [2ck][2s][4096][768] bf16 (X1 slot, dead in MLP stage)
  float* OUT = (float*)d_out;

  dim3 tb(32, 8);
  wconv<true><<<dim3(72, 24, 4), tb, 0, stream>>>(w_qkv_a, w_qkv_b, cw_qkv_a, cw_qkv_b,
      WQKV, WQKV + 1769472, WQKV + 2 * 1769472, WQKV + 3 * 1769472, 768, 2304);
  wconv<false><<<dim3(24, 24, 4), tb, 0, stream>>>(w_out_a, w_out_b, cw_out_a, cw_out_b,
      WOUT, WOUT + 589824, WOUT + 2 * 589824, WOUT + 3 * 589824, 768, 768);
  wconv<false><<<dim3(96, 24, 2), tb, 0, stream>>>(w1a, w1b, nullptr, nullptr,
      W1, W1 + 2359296, nullptr, nullptr, 768, 3072);
  wconv<false><<<dim3(24, 96, 2), tb, 0, stream>>>(w2a, w2b, nullptr, nullptr,
      W2, W2 + 2359296, nullptr, nullptr, 3072, 768);

  // ---- self-attention stage
  ln2<<<8192, 192, 0, stream>>>(x_in, y_in, lng[0], lnb[0], lng[3], lnb[3], XN);
  gemm_k<0><<<dim3(32, 18, 2), 256, 0, stream>>>(XN, XN + 3145728, WQKV, WQKV + 1769472,
      QKV, nullptr, nullptr, nullptr, nullptr, nullptr, 2304, 768, 768, 768);
  attn_k<<<dim3(768, 1, 1), 512, 0, stream>>>(QKV, AO, 0);
  gemm_k<1><<<dim3(32, 6, 2), 256, 0, stream>>>(AO, AO + 3145728, WOUT, WOUT + 589824,
      X1, X1 + 3145728, nullptr, nullptr, x_in, y_in, 768, 768, 768, 768);
  // ---- cross-attention stage
  ln2<<<8192, 192, 0, stream>>>(X1, X1 + 3145728, lng[1], lnb[1], lng[4], lnb[4], XN);
  gemm_k<0><<<dim3(32, 18, 2), 256, 0, stream>>>(XN, XN + 3145728, WQKV + 2 * 1769472, WQKV + 3 * 1769472,
      QKV, nullptr, nullptr, nullptr, nullptr, nullptr, 2304, 768, 768, 768);
  attn_k<<<dim3(768, 1, 1), 512, 0, stream>>>(QKV, AO, 1);
  gemm_k<1><<<dim3(32, 6, 2), 256, 0, stream>>>(AO, AO + 3145728, WOUT + 2 * 589824, WOUT + 3 * 589824,
      X2, X2 + 3145728, nullptr, nullptr, X1, X1 + 3145728, 768, 768, 768, 768);
  // ---- MLP stage
  ln2<<<8192, 192, 0, stream>>>(X2, X2 + 3145728, lng[2], lnb[2], lng[5], lnb[5], XN);
  gemm_k<2><<<dim3(32, 24, 2), 256, 0, stream>>>(XN, XN + 3145728, W1, W1 + 2359296,
      MLPH, MLPH + 12582912, b1a, b1b, nullptr, nullptr, 3072, 768, 768, 768);
  // MLP2 split-K=2: z = ck*2 + s, each chunk K=1536 (lda/ldb = full 3072)
  gemm_k<3><<<dim3(32, 6, 4), 256, 0, stream>>>(MLPH, MLPH + 12582912, W2, W2 + 2359296,
      Pbuf, nullptr, nullptr, nullptr, nullptr, nullptr, 768, 1536, 3072, 3072);
  mlp2c<<<8192, 192, 0, stream>>>(Pbuf, X2, b2a, b2b, OUT);
}